// Round 16
// baseline (62.525 us; speedup 1.0000x reference)
//
#include <hip/hip_runtime.h>
#include <math.h>

#define NB 16
#define NCTX 2048
#define NTEST 1024
#define NCTX_TOT (NB*NCTX)      /* 32768 */
#define NTEST_TOT (NB*NTEST)    /* 16384 */
#define NTOT (NCTX_TOT + NTEST_TOT) /* 49152 */

typedef _Float16 half8 __attribute__((ext_vector_type(8)));
typedef _Float16 half4 __attribute__((ext_vector_type(4)));
typedef float f32x4 __attribute__((ext_vector_type(4)));

__device__ __forceinline__ float gelu_f(float x) {
  float x3 = x * x * x;
  float y = 0.7978845608028654f * fmaf(0.044715f, x3, x);
  float e = __expf(2.0f * y);
  float th = 1.0f - 2.0f * __builtin_amdgcn_rcpf(e + 1.0f);
  return 0.5f * x * (1.0f + th);
}

__device__ __forceinline__ void fma4(float4& a, float s, float4 w) {
  a.x = fmaf(s, w.x, a.x);
  a.y = fmaf(s, w.y, a.y);
  a.z = fmaf(s, w.z, a.z);
  a.w = fmaf(s, w.w, a.w);
}

__device__ __forceinline__ float4 ldg4(const float* p) {
  return *reinterpret_cast<const float4*>(p);
}

__device__ __forceinline__ unsigned fkey(float f) {
  unsigned u = __float_as_uint(f);
  return (u & 0x80000000u) ? ~u : (u ^ 0x80000000u);
}
__device__ __forceinline__ float unfkey(unsigned k) {
  return (k & 0x80000000u) ? __uint_as_float(k ^ 0x80000000u)
                           : __uint_as_float(~k);
}

// ---------------------------------------------------------------------------
// Fused KNN + weight-prep kernel (R12 verbatim).
// ---------------------------------------------------------------------------
__global__ __launch_bounds__(256, 3) void knn_prep_kernel(
    const float* __restrict__ s_ctx, const float* __restrict__ s_test,
    int* __restrict__ senders,
    const float* __restrict__ W1, const float* __restrict__ b1,
    const float* __restrict__ emb,
    const float* __restrict__ W2, const float* __restrict__ W3,
    const float* __restrict__ Wg,
    const float* __restrict__ H1, const float* __restrict__ H2,
    _Float16* __restrict__ W2P, _Float16* __restrict__ W3P,
    _Float16* __restrict__ WgP,
    _Float16* __restrict__ H1P, _Float16* __restrict__ H2P,
    float* __restrict__ ctype)
{
  __shared__ __align__(16) unsigned long long sk[4][128];   // 4096 B
  const int blk = blockIdx.x;

  if (blk < 40) {
    // ---------------- prep role: one pack item per thread ----------------
    const int t = blk*256 + (int)threadIdx.x;     // 0..10239
    if (t < 4096) {            // W2: N=128, KS=8
      int i = t;
      int j = i >> 9, ks = (i >> 6) & 7, l = i & 63;
      int col = 16*j + (l & 15);
      int k0  = ks*32 + (l >> 4)*8;
      half8 o;
      #pragma unroll
      for (int e = 0; e < 8; ++e) o[e] = (_Float16)W2[(k0 + e)*128 + col];
      *reinterpret_cast<half8*>(&W2P[(size_t)i*8]) = o;
    } else if (t < 5120) {     // W3: N=64, KS=4
      int i = t - 4096;
      int j = i >> 8, ks = (i >> 6) & 3, l = i & 63;
      int col = 16*j + (l & 15);
      int k0  = ks*32 + (l >> 4)*8;
      half8 o;
      #pragma unroll
      for (int e = 0; e < 8; ++e) o[e] = (_Float16)W3[(k0 + e)*64 + col];
      *reinterpret_cast<half8*>(&W3P[(size_t)i*8]) = o;
    } else if (t < 5632) {     // Wg: N=64, KS=2
      int i = t - 5120;
      int j = i >> 7, ks = (i >> 6) & 1, l = i & 63;
      int col = 16*j + (l & 15);
      int k0  = ks*32 + (l >> 4)*8;
      half8 o;
      #pragma unroll
      for (int e = 0; e < 8; ++e) o[e] = (_Float16)Wg[(k0 + e)*64 + col];
      *reinterpret_cast<half8*>(&WgP[(size_t)i*8]) = o;
    } else if (t < 7680) {     // H1: N=256, KS=2
      int i = t - 5632;
      int j = i >> 7, ks = (i >> 6) & 1, l = i & 63;
      int col = 16*j + (l & 15);
      int k0  = ks*32 + (l >> 4)*8;
      half8 o;
      #pragma unroll
      for (int e = 0; e < 8; ++e) o[e] = (_Float16)H1[(k0 + e)*256 + col];
      *reinterpret_cast<half8*>(&H1P[(size_t)i*8]) = o;
    } else if (t < 9728) {     // H2: N=64, KS=8
      int i = t - 7680;
      int j = i >> 9, ks = (i >> 6) & 7, l = i & 63;
      int col = 16*j + (l & 15);
      int k0  = ks*32 + (l >> 4)*8;
      half8 o;
      #pragma unroll
      for (int e = 0; e < 8; ++e) o[e] = (_Float16)H2[(k0 + e)*64 + col];
      *reinterpret_cast<half8*>(&H2P[(size_t)i*8]) = o;
    } else {                   // ctype [2][256]
      int i = t - 9728;        // 0..511
      int ty = i >> 8, c = i & 255;
      float acc = b1[c];
      #pragma unroll
      for (int k = 0; k < 4; ++k) acc = fmaf(emb[ty*4 + k], W1[k*256 + c], acc);
      ctype[i] = acc;
    }
    return;
  }

  // ---------------- knn role ----------------------------------------------
  const int t    = threadIdx.x;
  const int lane = t & 63;
  const int w    = t >> 6;                       // 0..3
  const int b0   = blk - 40;                     // 0..4095
  const int unit = (b0 & 7)*512 + (b0 >> 3);     // XCD-bijective swizzle
  const int bb   = unit >> 8;                    // batch
  const int q    = (unit & 255) * 4 + w;         // 0..1023
  const int trow = bb * NTEST + q;

  const float* cb = s_ctx + (size_t)bb * NCTX * 2;
  const float qx = s_test[(size_t)trow*2];
  const float qy = s_test[(size_t)trow*2 + 1];
  const float qq = __fadd_rn(__fmul_rn(qx,qx), __fmul_rn(qy,qy));

  // batched loads: all 32 in flight before any compute
  float2 p[32];
  #pragma unroll
  for (int it = 0; it < 32; ++it)
    p[it] = *reinterpret_cast<const float2*>(&cb[2*(it*64 + lane)]);

  float d[32];
  float mn = 3.4e38f;
  #pragma unroll
  for (int it = 0; it < 32; ++it) {
    float ss  = __fadd_rn(__fmul_rn(p[it].x,p[it].x), __fmul_rn(p[it].y,p[it].y));
    float dot = __fadd_rn(__fmul_rn(qx, p[it].x), __fmul_rn(qy, p[it].y));
    float d2  = __fsub_rn(__fadd_rn(qq, ss), __fmul_rn(2.0f, dot));
    d[it] = d2;
    mn = fminf(mn, d2);
  }

  // threshold: bitonic ascending sort of 64 lane-min keys, take sorted[15]
  unsigned v = fkey(mn);
  #pragma unroll
  for (int k = 2; k <= 64; k <<= 1) {
    #pragma unroll
    for (int j = k >> 1; j >= 1; j >>= 1) {
      unsigned pv = (unsigned)__shfl_xor((int)v, j);
      bool up      = ((lane & k) == 0);
      bool lowHalf = ((lane & j) == 0);
      bool keepMin = (lowHalf == up);
      unsigned mnv = v < pv ? v : pv;
      unsigned mxv = v < pv ? pv : v;
      v = keepMin ? mnv : mxv;
    }
  }
  const float Tf = unfkey((unsigned)__shfl((int)v, 15));

  // compaction: per-lane count -> shfl_up prefix -> per-lane ordered writes
  int cnt = 0;
  #pragma unroll
  for (int it = 0; it < 32; ++it) cnt += (int)(d[it] <= Tf);
  int inc = cnt;
  #pragma unroll
  for (int o = 1; o < 64; o <<= 1) {
    int y = __shfl_up(inc, o);
    if (lane >= o) inc += y;
  }
  const int S = __shfl(inc, 63);        // uniform; S >= 16 guaranteed
  int pos = inc - cnt;                  // exclusive prefix
  #pragma unroll
  for (int it = 0; it < 32; ++it) {
    if (d[it] <= Tf) {
      if (pos < 128)
        sk[w][pos] = ((unsigned long long)fkey(d[it]) << 32)
                   | (unsigned)(it*64 + lane);       // idx in [0,2047]
      ++pos;
    }
  }

  if (S <= 32) {
    if (lane >= S && lane < 32) sk[w][lane] = ~0ULL;
    unsigned long long pm = sk[w][lane & 31];
    unsigned long long kv[32];
    #pragma unroll
    for (int j = 0; j < 32; ++j) kv[j] = sk[w][j];
    int r0 = 0;
    #pragma unroll
    for (int j = 0; j < 32; ++j)
      r0 += (int)(kv[j] < pm);          // (key,idx) lexicographic rank
    if (lane < S && r0 < 16)
      senders[(size_t)trow*16 + r0] = bb*NCTX + (int)(pm & 0xFFFFFFFFu);
  } else if (S <= 128) {
    unsigned long long p0 = (lane      < S) ? sk[w][lane]      : ~0ULL;
    unsigned long long p1 = (lane + 64 < S) ? sk[w][lane + 64] : ~0ULL;
    int r0 = 0, r1 = 0;
    for (int j = 0; j < S; ++j) {       // broadcast LDS reads
      unsigned long long kj = sk[w][j];
      r0 += (int)(kj < p0);
      r1 += (int)(kj < p1);
    }
    if (lane < S && r0 < 16)
      senders[(size_t)trow*16 + r0] = bb*NCTX + (int)(p0 & 0xFFFFFFFFu);
    if (lane + 64 < S && r1 < 16)
      senders[(size_t)trow*16 + r1] = bb*NCTX + (int)(p1 & 0xFFFFFFFFu);
  } else {
    if (lane == 0) {
      float dist[16]; int ind[16];
      #pragma unroll
      for (int j=0;j<16;++j){ dist[j]=3.4e38f; ind[j]=0; }
      for (int c = 0; c < NCTX; ++c) {
        float2 pp = *reinterpret_cast<const float2*>(&cb[2*c]);
        float ss  = __fadd_rn(__fmul_rn(pp.x,pp.x), __fmul_rn(pp.y,pp.y));
        float dot = __fadd_rn(__fmul_rn(qx, pp.x), __fmul_rn(qy, pp.y));
        float d2  = __fsub_rn(__fadd_rn(qq, ss), __fmul_rn(2.0f, dot));
        if (d2 < dist[15]) {
          float dj = d2; int ij = c;
          #pragma unroll
          for (int j = 0; j < 16; ++j) {
            bool sw = dj < dist[j];
            float td = dist[j]; int ti = ind[j];
            dist[j] = sw ? dj : td;  ind[j] = sw ? ij : ti;
            dj = sw ? td : dj;       ij = sw ? ti : ij;
          }
        }
      }
      for (int j = 0; j < 16; ++j)
        senders[(size_t)trow*16 + j] = bb*NCTX + ind[j];
    }
  }
}

// ---------------------------------------------------------------------------
// node_mlp kernel R16: LDS pack staging. Same shape as R12 (4 waves, 4 row
// tiles, grid 768) but W2P/W3P/WgP fragments are staged into a 16 KB LDS
// buffer ONCE PER BLOCK (cooperative copy + barriers) and consumed by all
// 4 waves -> pack L2 traffic /4 (264 MB -> 66 MB; mlp measured at the L2
// BW ceiling). MFMA accumulation order unchanged -> bit-identical.
// LDS 51200 -> 3 blocks/CU x 256 CU = 768 = grid in one round; (256,3).
// ---------------------------------------------------------------------------
__global__ __launch_bounds__(256, 3) void mlp_kernel(
    const float* __restrict__ s_ctx, const float* __restrict__ f_ctx,
    const float* __restrict__ s_test,
    const float* __restrict__ ctype, const float* __restrict__ W1,
    const _Float16* __restrict__ W2P, const float* __restrict__ b2,
    const _Float16* __restrict__ W3P, const float* __restrict__ b3,
    const float* __restrict__ ln_g, const float* __restrict__ ln_b,
    const _Float16* __restrict__ WgP,
    const float* __restrict__ a_src, const float* __restrict__ a_dst,
    float* __restrict__ nodes, _Float16* __restrict__ xph,
    float* __restrict__ xps, float* __restrict__ xpd)
{
  __shared__ __align__(16) char smem[34816];
  __shared__ __align__(16) _Float16 stg[8192];   // 16 KB staging buffer
  const int t    = threadIdx.x;
  const int lane = t & 63;
  const int w    = t >> 6;
  const int id   = blockIdx.x;        // 0..767
  char* slice = smem + w * 8704;
  _Float16* h1t  = reinterpret_cast<_Float16*>(slice);     // [16][264]
  float (*xin)[4] = reinterpret_cast<float(*)[4]>(slice + 8448);
  _Float16* h2   = h1t;               // overlay after h1 consumed
  _Float16* nodh = h1t + 16*136;
  const int cn = lane & 15;
  const int kg = lane >> 4;
  const int m0 = (id*4 + w) * 16;
  const bool is_ctx = (m0 < NCTX_TOT);   // uniform per wave

  { // stage per-row inputs
    int r = lane >> 2, c = lane & 3;
    int n = m0 + r;
    float v;
    if (is_ctx) v = (c < 2) ? s_ctx[2*(size_t)n + c] : f_ctx[2*(size_t)n + (c-2)];
    else { int tn = n - NCTX_TOT; v = (c < 2) ? s_test[2*(size_t)tn + c] : 0.f; }
    xin[r][c] = v;
  }

  { // L1
    const int c0 = lane * 4;
    float4 w4 = ldg4(&W1[4*256 + c0]);
    float4 w5 = ldg4(&W1[5*256 + c0]);
    float4 w6 = ldg4(&W1[6*256 + c0]);
    float4 w7 = ldg4(&W1[7*256 + c0]);
    float4 cbv = ldg4(&ctype[(is_ctx ? 256 : 0) + c0]);
    #pragma unroll
    for (int r = 0; r < 16; ++r) {
      float4 xi = *reinterpret_cast<const float4*>(&xin[r][0]);
      float4 a = cbv;
      fma4(a, xi.x, w4); fma4(a, xi.y, w5);
      fma4(a, xi.z, w6); fma4(a, xi.w, w7);
      half4 o = { (_Float16)gelu_f(a.x), (_Float16)gelu_f(a.y),
                  (_Float16)gelu_f(a.z), (_Float16)gelu_f(a.w) };
      *reinterpret_cast<half4*>(&h1t[r*264 + c0]) = o;
    }
  }

  { // L2: 4 stage-rounds of 2 ks (16 KB each), all waves consume from LDS
    f32x4 acc[8];
    #pragma unroll
    for (int j = 0; j < 8; ++j) {
      float bv = b2[16*j + cn];
      acc[j] = (f32x4){bv, bv, bv, bv};
    }
    const _Float16* aP = h1t + cn*264 + kg*8;
    for (int r4 = 0; r4 < 4; ++r4) {
      __syncthreads();   // previous chunk fully consumed
      // stage 16 items: k = j*2+kk -> W2P item (j*8 + 2*r4 + kk)
      #pragma unroll
      for (int u = 0; u < 4; ++u) {
        int uu = u*256 + t;            // 0..1023 half8-units
        int k  = uu >> 6;              // 0..15
        int o  = (uu & 63) * 8;
        int j  = k >> 1, kk = k & 1;
        *reinterpret_cast<half8*>(&stg[k*512 + o]) =
          *reinterpret_cast<const half8*>(&W2P[(size_t)(j*8 + 2*r4 + kk)*512 + o]);
      }
      __syncthreads();
      #pragma unroll
      for (int kk = 0; kk < 2; ++kk) {
        const int ks = 2*r4 + kk;
        half8 a = *reinterpret_cast<const half8*>(aP + ks*32);
        #pragma unroll
        for (int j = 0; j < 8; ++j) {
          half8 b = *reinterpret_cast<const half8*>(&stg[(j*2 + kk)*512 + lane*8]);
          acc[j] = __builtin_amdgcn_mfma_f32_16x16x32_f16(a, b, acc[j], 0, 0, 0);
        }
      }
    }
    #pragma unroll
    for (int j = 0; j < 8; ++j)
      #pragma unroll
      for (int r = 0; r < 4; ++r) {
        int m = kg*4 + r;
        h2[m*136 + 16*j + cn] = (_Float16)gelu_f(acc[j][r]);
      }
  }

  { // L3 + LN: stage all of W3P (16 KB) once
    __syncthreads();   // W2P chunk consumed by all waves
    #pragma unroll
    for (int u = 0; u < 4; ++u) {
      int uu = u*256 + t;              // 0..1023 half8-units (8192 halves)
      int o  = uu * 8;
      *reinterpret_cast<half8*>(&stg[o]) =
        *reinterpret_cast<const half8*>(&W3P[o]);
    }
    __syncthreads();

    f32x4 acc[4];
    #pragma unroll
    for (int j = 0; j < 4; ++j) {
      float bv = b3[16*j + cn];
      acc[j] = (f32x4){bv, bv, bv, bv};
    }
    const _Float16* aP = h2 + cn*136 + kg*8;
    #pragma unroll
    for (int ks = 0; ks < 4; ++ks) {
      half8 a = *reinterpret_cast<const half8*>(aP + ks*32);
      #pragma unroll
      for (int j = 0; j < 4; ++j) {
        half8 b = *reinterpret_cast<const half8*>(&stg[(j*4 + ks)*512 + lane*8]);
        acc[j] = __builtin_amdgcn_mfma_f32_16x16x32_f16(a, b, acc[j], 0, 0, 0);
      }
    }
    float gv[4], bvv[4];
    #pragma unroll
    for (int j = 0; j < 4; ++j) { gv[j] = ln_g[16*j+cn]; bvv[j] = ln_b[16*j+cn]; }
    const bool is_test = !is_ctx;
    #pragma unroll
    for (int r = 0; r < 4; ++r) {
      float sv = 0.f, sq = 0.f;
      #pragma unroll
      for (int j = 0; j < 4; ++j) {
        float v = acc[j][r];
        sv += v; sq += v*v;
      }
      #pragma unroll
      for (int o = 1; o < 16; o <<= 1) {
        sv += __shfl_xor(sv, o);
        sq += __shfl_xor(sq, o);
      }
      float mean = sv * (1.0f/64.0f);
      float var  = sq * (1.0f/64.0f) - mean*mean;
      float rstd = rsqrtf(var + 1e-6f);
      int m = kg*4 + r;
      #pragma unroll
      for (int j = 0; j < 4; ++j) {
        float v = (acc[j][r] - mean) * rstd * gv[j] + bvv[j];
        nodh[m*72 + 16*j + cn] = (_Float16)v;
        if (is_test)
          nodes[(size_t)(m0 + m)*64 + 16*j + cn] = v;
      }
    }
  }

  { // xp = LN @ Wg: stage all of WgP (8 KB) once
    __syncthreads();   // W3P staging consumed
    #pragma unroll
    for (int u = 0; u < 2; ++u) {
      int uu = u*256 + t;              // 0..511 half8-units (4096 halves)
      int o  = uu * 8;
      *reinterpret_cast<half8*>(&stg[o]) =
        *reinterpret_cast<const half8*>(&WgP[o]);
    }
    __syncthreads();

    f32x4 acc[4];
    #pragma unroll
    for (int j = 0; j < 4; ++j) acc[j] = (f32x4){0.f, 0.f, 0.f, 0.f};
    const _Float16* aP = nodh + cn*72 + kg*8;
    half8 a0 = *reinterpret_cast<const half8*>(aP);
    half8 a1 = *reinterpret_cast<const half8*>(aP + 32);
    #pragma unroll
    for (int j = 0; j < 4; ++j) {
      half8 b = *reinterpret_cast<const half8*>(&stg[(j*2 + 0)*512 + lane*8]);
      acc[j] = __builtin_amdgcn_mfma_f32_16x16x32_f16(a0, b, acc[j], 0, 0, 0);
    }
    #pragma unroll
    for (int j = 0; j < 4; ++j) {
      half8 b = *reinterpret_cast<const half8*>(&stg[(j*2 + 1)*512 + lane*8]);
      acc[j] = __builtin_amdgcn_mfma_f32_16x16x32_f16(a1, b, acc[j], 0, 0, 0);
    }
    #pragma unroll
    for (int r = 0; r < 4; ++r) {
      int m = kg*4 + r;
      #pragma unroll
      for (int j = 0; j < 4; ++j)
        xph[(size_t)(m0 + m)*64 + 16*j + cn] = (_Float16)acc[j][r];
    }
    const float* av = is_ctx ? a_src : a_dst;
    float av0 = av[cn], av1 = av[16+cn], av2 = av[32+cn], av3 = av[48+cn];
    #pragma unroll
    for (int r = 0; r < 4; ++r) {
      float p0 = acc[0][r]*av0, p1 = acc[1][r]*av1;
      float p2 = acc[2][r]*av2, p3 = acc[3][r]*av3;
      #pragma unroll
      for (int o = 1; o < 16; o <<= 1) {
        p0 += __shfl_xor(p0, o); p1 += __shfl_xor(p1, o);
        p2 += __shfl_xor(p2, o); p3 += __shfl_xor(p3, o);
      }
      if (cn == 0) {
        int m = kg*4 + r;
        float4 v = make_float4(p0, p1, p2, p3);
        if (is_ctx)
          *reinterpret_cast<float4*>(&xps[(size_t)(m0 + m)*4]) = v;
        else
          *reinterpret_cast<float4*>(&xpd[(size_t)(m0 + m - NCTX_TOT)*4]) = v;
      }
    }
  }
}

// ---------------------------------------------------------------------------
// Back kernel (R15 verbatim): 4 waves per block share one 16-row tile
// (grid 1024 x 256). attn 4 rows/wave; pack fragments read once per block;
// L1 wave wv owns j-tiles wv*4..wv*4+3; L2 wave wv owns j = wv; 4-partial
// L3 combine via LDS.
// ---------------------------------------------------------------------------
__global__ __launch_bounds__(256, 4) void back_kernel(
    const float* __restrict__ s_ctx, const float* __restrict__ s_test,
    const _Float16* __restrict__ xph, const int* __restrict__ senders,
    const float* __restrict__ xps, const float* __restrict__ xpd,
    const float* __restrict__ We, const float* __restrict__ be,
    const float* __restrict__ nodes,
    const _Float16* __restrict__ H1P, const float* __restrict__ c1,
    const _Float16* __restrict__ H2P, const float* __restrict__ c2,
    const float* __restrict__ H3, const float* __restrict__ c3,
    float* __restrict__ outp)
{
  __shared__ __align__(16) _Float16 xinh[16*72];   // 2304 B (all 16 rows valid)
  __shared__ __align__(16) _Float16 h1[16*264];    // 8448 B
  __shared__ float pp[4][16][2];                   // 512 B L3 partials
  const int tid  = threadIdx.x;       // 0..255
  const int lane = tid & 63;
  const int wv   = tid >> 6;          // 0..3
  const int cn   = lane & 15;
  const int kg   = lane >> 4;
  const int bid  = blockIdx.x;                    // 1024
  const int L    = (bid & 7)*128 + (bid >> 3);    // XCD-contiguous
  const int row0 = L * 16;                        // test-local row base

  { // ---- attn: wave wv handles rows wv*4 .. wv*4+3 ----
    const int h  = kg;
    const int kk = cn;
    const int hb = lane & 48;
    const float we0 = We[h], we1 = We[4+h], beh = be[h];
    for (int rr = 0; rr < 4; ++rr) {
      const int rl   = wv*4 + rr;
      const int trow = row0 + rl;
      int s = senders[(size_t)trow*16 + kk];
      s = (s < 0) ? 0 : ((s >= NCTX_TOT) ? NCTX_TOT - 1 : s);  // safety clamp
      float pre = xps[(size_t)s*4 + h] + xpd[(size_t)trow*4 + h];
      float lr  = pre >= 0.f ? pre : 0.2f * pre;
      const float qx = s_test[(size_t)trow*2];
      const float qy = s_test[(size_t)trow*2 + 1];
      float ex = qx - s_ctx[(size_t)s*2];
      float ey = qy - s_ctx[(size_t)s*2 + 1];
      float sc = lr + fmaf(ex, we0, fmaf(ey, we1, beh));
      float mx = sc;
      #pragma unroll
      for (int o = 1; o < 16; o <<= 1) mx = fmaxf(mx, __shfl_xor(mx, o));
      float e = __expf(sc - mx);
      float sum = e;
      #pragma unroll
      for (int o = 1; o < 16; o <<= 1) sum += __shfl_xor(sum, o);
      float alpha = e / sum;
      // PV: lane = h*16+d reads alphas of its head via in-group shfl
      float outv = 0.f;
      #pragma unroll
      for (int k = 0; k < 16; ++k) {
        int   sk = __shfl(s, k);            // same across head groups
        float al = __shfl(alpha, hb + k);
        outv = fmaf(al, (float)xph[(size_t)sk*64 + lane], outv);
      }
      float xv = nodes[(size_t)(NCTX_TOT + trow)*64 + lane] + outv;
      xinh[rl*72 + lane] = (_Float16)xv;
    }
  }

  __syncthreads();

  // ---- head L1 (K=64, N=256): wave wv owns j-tiles wv*4 .. wv*4+3 ----
  {
    const _Float16* aP  = xinh + cn*72 + kg*8;
    const _Float16* bQ1 = H1P + lane*8;
    half8 a0 = *reinterpret_cast<const half8*>(aP);
    half8 a1 = *reinterpret_cast<const half8*>(aP + 32);
    f32x4 acc[4];
    #pragma unroll
    for (int j2 = 0; j2 < 4; ++j2) {
      const int jj = wv*4 + j2;
      float bv = c1[16*jj + cn];
      acc[j2] = (f32x4){bv, bv, bv, bv};
    }
    half8 b0[4], b1[4];
    #pragma unroll
    for (int j2 = 0; j2 < 4; ++j2) {
      const int jj = wv*4 + j2;
      b0[j2] = *reinterpret_cast<const half8*>(bQ1 + (jj*2 + 0)*512);
      b1[j2] = *reinterpret_cast<const half8*>(bQ1 + (jj*2 + 1)*512);
    }
    #pragma unroll
    for (int j2 = 0; j2 < 4; ++j2)
      acc[j2] = __builtin_amdgcn_mfma_f32_16x16x32_f16(a0, b0[j2], acc[j2], 0, 0, 0);
    #pragma unroll
    for (int j2 = 0; j2 < 4; ++j2)
      acc[j2] = __builtin_amdgcn_mfma_f32_16x16x32_f16(a1, b1[j2], acc[j2], 0, 0, 0);
    #pragma unroll
    for (int j2 = 0; j2 < 4; ++j2) {
      const int jj = wv*4 + j2;
      #pragma unroll
      for (int r = 0; r < 4; ++r)
        h1[(kg*4 + r)*264 + 16*jj + cn] = (_Float16)gelu_f(acc[j2][r]);
    }
  }

  __syncthreads();

  // ---- head L2 (K=256, N=64): wave wv owns j = wv, + L3 partials ----
  {
    f32x4 acc;
    {
      float bv = c2[16*wv + cn];
      acc = (f32x4){bv, bv, bv, bv};
    }
    const _Float16* aP  = h1 + cn*264 + kg*8;
    const _Float16* bQ2 = H2P + lane*8;
    half8 bb = *reinterpret_cast<const half8*>(bQ2 + wv*4096);
    #pragma unroll
    for (int ks = 0; ks < 8; ++ks) {
      half8 a = *reinterpret_cast<const half8*>(aP + ks*32);
      half8 bn;
      if (ks < 7)
        bn = *reinterpret_cast<const half8*>(bQ2 + wv*4096 + (ks+1)*512);
      acc = __builtin_amdgcn_mfma_f32_16x16x32_f16(a, bb, acc, 0, 0, 0);
      if (ks < 7) bb = bn;
    }
    // L3 partials: gelu, dot with this wave's H3 column slice, butterfly
    float h30 = H3[(16*wv + cn)*2 + 0];
    float h31 = H3[(16*wv + cn)*2 + 1];
    #pragma unroll
    for (int r = 0; r < 4; ++r) {
      float g  = gelu_f(acc[r]);
      float p0 = g * h30;
      float p1 = g * h31;
      #pragma unroll
      for (int o = 1; o < 16; o <<= 1) {
        p0 += __shfl_xor(p0, o);
        p1 += __shfl_xor(p1, o);
      }
      if (cn == 0) {
        pp[wv][kg*4 + r][0] = p0;
        pp[wv][kg*4 + r][1] = p1;
      }
    }
  }

  __syncthreads();

  // ---- combine partials + softplus + store (wave 0, lanes 0..15) ----
  if (wv == 0 && lane < 16) {
    const float c30 = c3[0], c31 = c3[1];
    float m  = pp[0][lane][0] + pp[1][lane][0] + pp[2][lane][0]
             + pp[3][lane][0] + c30;
    float sa = pp[0][lane][1] + pp[1][lane][1] + pp[2][lane][1]
             + pp[3][lane][1] + c31;
    float sv = fmaxf(sa, 0.f) + log1pf(__expf(-fabsf(sa)));  // softplus
    int row = row0 + lane;
    outp[(size_t)row*2 + 0] = m;
    outp[(size_t)row*2 + 1] = sv;
  }
}

// ---------------------------------------------------------------------------
extern "C" void kernel_launch(void* const* d_in, const int* in_sizes, int n_in,
                              void* d_out, int out_size, void* d_ws, size_t ws_size,
                              hipStream_t stream) {
  const float* s_ctx  = (const float*)d_in[0];
  const float* f_ctx  = (const float*)d_in[1];
  const float* s_test = (const float*)d_in[2];
  const float* emb    = (const float*)d_in[3];
  const float* W1 = (const float*)d_in[4];
  const float* b1 = (const float*)d_in[5];
  const float* W2 = (const float*)d_in[6];
  const float* b2 = (const float*)d_in[7];
  const float* W3 = (const float*)d_in[8];
  const float* b3 = (const float*)d_in[9];
  const float* ln_g = (const float*)d_in[10];
  const float* ln_b = (const float*)d_in[11];
  const float* Wg = (const float*)d_in[12];
  const float* a_src = (const float*)d_in[13];
  const float* a_dst = (const float*)d_in[14];
  const float* We = (const float*)d_in[15];
  const float* be = (const float*)d_in[16];
  const float* H1 = (const float*)d_in[17];
  const float* c1 = (const float*)d_in[18];
  const float* H2 = (const float*)d_in[19];
  const float* c2 = (const float*)d_in[20];
  const float* H3 = (const float*)d_in[21];
  const float* c3 = (const float*)d_in[22];

  float* nodes   = (float*)d_ws;                       // NTOT x 64 fp32
  _Float16* xph  = (_Float16*)(nodes + (size_t)NTOT*64);  // NTOT x 64 fp16
  int*   senders = (int*)(xph + (size_t)NTOT*64);      // NTEST_TOT x 16
  _Float16* W2P  = (_Float16*)(senders + (size_t)NTEST_TOT*16); // 32768 halves
  _Float16* W3P  = W2P + 32768;                        // 8192 halves
  _Float16* WgP  = W3P + 8192;                         // 4096 halves
  _Float16* H1P  = WgP + 4096;                         // 16384 halves
  _Float16* H2P  = H1P + 16384;                        // 16384 halves
  float*   ctype = (float*)(H2P + 16384);              // [2][256]
  float*   xps   = ctype + 512;                        // NCTX_TOT x 4
  float*   xpd   = xps + (size_t)NCTX_TOT*4;           // NTEST_TOT x 4
  float* outp    = (float*)d_out;

  hipLaunchKernelGGL(knn_prep_kernel, dim3(4136), dim3(256), 0, stream,
                     s_ctx, s_test, senders,
                     W1, b1, emb, W2, W3, Wg, H1, H2,
                     W2P, W3P, WgP, H1P, H2P, ctype);
  hipLaunchKernelGGL(mlp_kernel, dim3(768), dim3(256), 0, stream,
                     s_ctx, f_ctx, s_test, ctype, W1,
                     W2P, b2, W3P, b3, ln_g, ln_b, WgP,
                     a_src, a_dst, nodes, xph, xps, xpd);
  hipLaunchKernelGGL(back_kernel, dim3(1024), dim3(256), 0, stream,
                     s_ctx, s_test, xph, senders, xps, xpd, We, be,
                     nodes, H1P, c1, H2P, c2, H3, c3, outp);
}

// Round 17
// 61.770 us; speedup vs baseline: 1.0122x; 1.0122x over previous
//
#include <hip/hip_runtime.h>
#include <math.h>

#define NB 16
#define NCTX 2048
#define NTEST 1024
#define NCTX_TOT (NB*NCTX)      /* 32768 */
#define NTEST_TOT (NB*NTEST)    /* 16384 */
#define NTOT (NCTX_TOT + NTEST_TOT) /* 49152 */

typedef _Float16 half8 __attribute__((ext_vector_type(8)));
typedef _Float16 half4 __attribute__((ext_vector_type(4)));
typedef float f32x4 __attribute__((ext_vector_type(4)));

__device__ __forceinline__ float gelu_f(float x) {
  float x3 = x * x * x;
  float y = 0.7978845608028654f * fmaf(0.044715f, x3, x);
  float e = __expf(2.0f * y);
  float th = 1.0f - 2.0f * __builtin_amdgcn_rcpf(e + 1.0f);
  return 0.5f * x * (1.0f + th);
}

__device__ __forceinline__ void fma4(float4& a, float s, float4 w) {
  a.x = fmaf(s, w.x, a.x);
  a.y = fmaf(s, w.y, a.y);
  a.z = fmaf(s, w.z, a.z);
  a.w = fmaf(s, w.w, a.w);
}

__device__ __forceinline__ float4 ldg4(const float* p) {
  return *reinterpret_cast<const float4*>(p);
}

__device__ __forceinline__ unsigned fkey(float f) {
  unsigned u = __float_as_uint(f);
  return (u & 0x80000000u) ? ~u : (u ^ 0x80000000u);
}
__device__ __forceinline__ float unfkey(unsigned k) {
  return (k & 0x80000000u) ? __uint_as_float(k ^ 0x80000000u)
                           : __uint_as_float(~k);
}

// ---------------------------------------------------------------------------
// Fused KNN + weight-prep kernel (R12 verbatim).
// ---------------------------------------------------------------------------
__global__ __launch_bounds__(256, 3) void knn_prep_kernel(
    const float* __restrict__ s_ctx, const float* __restrict__ s_test,
    int* __restrict__ senders,
    const float* __restrict__ W1, const float* __restrict__ b1,
    const float* __restrict__ emb,
    const float* __restrict__ W2, const float* __restrict__ W3,
    const float* __restrict__ Wg,
    const float* __restrict__ H1, const float* __restrict__ H2,
    _Float16* __restrict__ W2P, _Float16* __restrict__ W3P,
    _Float16* __restrict__ WgP,
    _Float16* __restrict__ H1P, _Float16* __restrict__ H2P,
    float* __restrict__ ctype)
{
  __shared__ __align__(16) unsigned long long sk[4][128];   // 4096 B
  const int blk = blockIdx.x;

  if (blk < 40) {
    // ---------------- prep role: one pack item per thread ----------------
    const int t = blk*256 + (int)threadIdx.x;     // 0..10239
    if (t < 4096) {            // W2: N=128, KS=8
      int i = t;
      int j = i >> 9, ks = (i >> 6) & 7, l = i & 63;
      int col = 16*j + (l & 15);
      int k0  = ks*32 + (l >> 4)*8;
      half8 o;
      #pragma unroll
      for (int e = 0; e < 8; ++e) o[e] = (_Float16)W2[(k0 + e)*128 + col];
      *reinterpret_cast<half8*>(&W2P[(size_t)i*8]) = o;
    } else if (t < 5120) {     // W3: N=64, KS=4
      int i = t - 4096;
      int j = i >> 8, ks = (i >> 6) & 3, l = i & 63;
      int col = 16*j + (l & 15);
      int k0  = ks*32 + (l >> 4)*8;
      half8 o;
      #pragma unroll
      for (int e = 0; e < 8; ++e) o[e] = (_Float16)W3[(k0 + e)*64 + col];
      *reinterpret_cast<half8*>(&W3P[(size_t)i*8]) = o;
    } else if (t < 5632) {     // Wg: N=64, KS=2
      int i = t - 5120;
      int j = i >> 7, ks = (i >> 6) & 1, l = i & 63;
      int col = 16*j + (l & 15);
      int k0  = ks*32 + (l >> 4)*8;
      half8 o;
      #pragma unroll
      for (int e = 0; e < 8; ++e) o[e] = (_Float16)Wg[(k0 + e)*64 + col];
      *reinterpret_cast<half8*>(&WgP[(size_t)i*8]) = o;
    } else if (t < 7680) {     // H1: N=256, KS=2
      int i = t - 5632;
      int j = i >> 7, ks = (i >> 6) & 1, l = i & 63;
      int col = 16*j + (l & 15);
      int k0  = ks*32 + (l >> 4)*8;
      half8 o;
      #pragma unroll
      for (int e = 0; e < 8; ++e) o[e] = (_Float16)H1[(k0 + e)*256 + col];
      *reinterpret_cast<half8*>(&H1P[(size_t)i*8]) = o;
    } else if (t < 9728) {     // H2: N=64, KS=8
      int i = t - 7680;
      int j = i >> 9, ks = (i >> 6) & 7, l = i & 63;
      int col = 16*j + (l & 15);
      int k0  = ks*32 + (l >> 4)*8;
      half8 o;
      #pragma unroll
      for (int e = 0; e < 8; ++e) o[e] = (_Float16)H2[(k0 + e)*64 + col];
      *reinterpret_cast<half8*>(&H2P[(size_t)i*8]) = o;
    } else {                   // ctype [2][256]
      int i = t - 9728;        // 0..511
      int ty = i >> 8, c = i & 255;
      float acc = b1[c];
      #pragma unroll
      for (int k = 0; k < 4; ++k) acc = fmaf(emb[ty*4 + k], W1[k*256 + c], acc);
      ctype[i] = acc;
    }
    return;
  }

  // ---------------- knn role ----------------------------------------------
  const int t    = threadIdx.x;
  const int lane = t & 63;
  const int w    = t >> 6;                       // 0..3
  const int b0   = blk - 40;                     // 0..4095
  const int unit = (b0 & 7)*512 + (b0 >> 3);     // XCD-bijective swizzle
  const int bb   = unit >> 8;                    // batch
  const int q    = (unit & 255) * 4 + w;         // 0..1023
  const int trow = bb * NTEST + q;

  const float* cb = s_ctx + (size_t)bb * NCTX * 2;
  const float qx = s_test[(size_t)trow*2];
  const float qy = s_test[(size_t)trow*2 + 1];
  const float qq = __fadd_rn(__fmul_rn(qx,qx), __fmul_rn(qy,qy));

  // batched loads: all 32 in flight before any compute
  float2 p[32];
  #pragma unroll
  for (int it = 0; it < 32; ++it)
    p[it] = *reinterpret_cast<const float2*>(&cb[2*(it*64 + lane)]);

  float d[32];
  float mn = 3.4e38f;
  #pragma unroll
  for (int it = 0; it < 32; ++it) {
    float ss  = __fadd_rn(__fmul_rn(p[it].x,p[it].x), __fmul_rn(p[it].y,p[it].y));
    float dot = __fadd_rn(__fmul_rn(qx, p[it].x), __fmul_rn(qy, p[it].y));
    float d2  = __fsub_rn(__fadd_rn(qq, ss), __fmul_rn(2.0f, dot));
    d[it] = d2;
    mn = fminf(mn, d2);
  }

  // threshold: bitonic ascending sort of 64 lane-min keys, take sorted[15]
  unsigned v = fkey(mn);
  #pragma unroll
  for (int k = 2; k <= 64; k <<= 1) {
    #pragma unroll
    for (int j = k >> 1; j >= 1; j >>= 1) {
      unsigned pv = (unsigned)__shfl_xor((int)v, j);
      bool up      = ((lane & k) == 0);
      bool lowHalf = ((lane & j) == 0);
      bool keepMin = (lowHalf == up);
      unsigned mnv = v < pv ? v : pv;
      unsigned mxv = v < pv ? pv : v;
      v = keepMin ? mnv : mxv;
    }
  }
  const float Tf = unfkey((unsigned)__shfl((int)v, 15));

  // compaction: per-lane count -> shfl_up prefix -> per-lane ordered writes
  int cnt = 0;
  #pragma unroll
  for (int it = 0; it < 32; ++it) cnt += (int)(d[it] <= Tf);
  int inc = cnt;
  #pragma unroll
  for (int o = 1; o < 64; o <<= 1) {
    int y = __shfl_up(inc, o);
    if (lane >= o) inc += y;
  }
  const int S = __shfl(inc, 63);        // uniform; S >= 16 guaranteed
  int pos = inc - cnt;                  // exclusive prefix
  #pragma unroll
  for (int it = 0; it < 32; ++it) {
    if (d[it] <= Tf) {
      if (pos < 128)
        sk[w][pos] = ((unsigned long long)fkey(d[it]) << 32)
                   | (unsigned)(it*64 + lane);       // idx in [0,2047]
      ++pos;
    }
  }

  if (S <= 32) {
    if (lane >= S && lane < 32) sk[w][lane] = ~0ULL;
    unsigned long long pm = sk[w][lane & 31];
    unsigned long long kv[32];
    #pragma unroll
    for (int j = 0; j < 32; ++j) kv[j] = sk[w][j];
    int r0 = 0;
    #pragma unroll
    for (int j = 0; j < 32; ++j)
      r0 += (int)(kv[j] < pm);          // (key,idx) lexicographic rank
    if (lane < S && r0 < 16)
      senders[(size_t)trow*16 + r0] = bb*NCTX + (int)(pm & 0xFFFFFFFFu);
  } else if (S <= 128) {
    unsigned long long p0 = (lane      < S) ? sk[w][lane]      : ~0ULL;
    unsigned long long p1 = (lane + 64 < S) ? sk[w][lane + 64] : ~0ULL;
    int r0 = 0, r1 = 0;
    for (int j = 0; j < S; ++j) {       // broadcast LDS reads
      unsigned long long kj = sk[w][j];
      r0 += (int)(kj < p0);
      r1 += (int)(kj < p1);
    }
    if (lane < S && r0 < 16)
      senders[(size_t)trow*16 + r0] = bb*NCTX + (int)(p0 & 0xFFFFFFFFu);
    if (lane + 64 < S && r1 < 16)
      senders[(size_t)trow*16 + r1] = bb*NCTX + (int)(p1 & 0xFFFFFFFFu);
  } else {
    if (lane == 0) {
      float dist[16]; int ind[16];
      #pragma unroll
      for (int j=0;j<16;++j){ dist[j]=3.4e38f; ind[j]=0; }
      for (int c = 0; c < NCTX; ++c) {
        float2 pp = *reinterpret_cast<const float2*>(&cb[2*c]);
        float ss  = __fadd_rn(__fmul_rn(pp.x,pp.x), __fmul_rn(pp.y,pp.y));
        float dot = __fadd_rn(__fmul_rn(qx, pp.x), __fmul_rn(qy, pp.y));
        float d2  = __fsub_rn(__fadd_rn(qq, ss), __fmul_rn(2.0f, dot));
        if (d2 < dist[15]) {
          float dj = d2; int ij = c;
          #pragma unroll
          for (int j = 0; j < 16; ++j) {
            bool sw = dj < dist[j];
            float td = dist[j]; int ti = ind[j];
            dist[j] = sw ? dj : td;  ind[j] = sw ? ij : ti;
            dj = sw ? td : dj;       ij = sw ? ti : ij;
          }
        }
      }
      for (int j = 0; j < 16; ++j)
        senders[(size_t)trow*16 + j] = bb*NCTX + ind[j];
    }
  }
}

// ---------------------------------------------------------------------------
// node_mlp kernel (R12/R15-proven verbatim). grid 768 x 256, each wave owns
// one 16-row tile. LDS 34816; (256,4).
// ---------------------------------------------------------------------------
__global__ __launch_bounds__(256, 4) void mlp_kernel(
    const float* __restrict__ s_ctx, const float* __restrict__ f_ctx,
    const float* __restrict__ s_test,
    const float* __restrict__ ctype, const float* __restrict__ W1,
    const _Float16* __restrict__ W2P, const float* __restrict__ b2,
    const _Float16* __restrict__ W3P, const float* __restrict__ b3,
    const float* __restrict__ ln_g, const float* __restrict__ ln_b,
    const _Float16* __restrict__ WgP,
    const float* __restrict__ a_src, const float* __restrict__ a_dst,
    float* __restrict__ nodes, _Float16* __restrict__ xph,
    float* __restrict__ xps, float* __restrict__ xpd)
{
  __shared__ __align__(16) char smem[34816];
  const int t    = threadIdx.x;
  const int lane = t & 63;
  const int w    = t >> 6;
  const int id   = blockIdx.x;        // 0..767
  char* slice = smem + w * 8704;
  _Float16* h1t  = reinterpret_cast<_Float16*>(slice);     // [16][264]
  float (*xin)[4] = reinterpret_cast<float(*)[4]>(slice + 8448);
  _Float16* h2   = h1t;               // overlay after h1 consumed
  _Float16* nodh = h1t + 16*136;
  const int cn = lane & 15;
  const int kg = lane >> 4;
  const int m0 = (id*4 + w) * 16;
  const bool is_ctx = (m0 < NCTX_TOT);   // uniform per wave

  const _Float16* bQ2 = W2P + lane*8;
  const _Float16* bQ3 = W3P + lane*8;
  const _Float16* bQg = WgP + lane*8;

  half8 bb2[8];
  #pragma unroll
  for (int j = 0; j < 8; ++j)
    bb2[j] = *reinterpret_cast<const half8*>(bQ2 + j*4096);

  { // stage per-row inputs
    int r = lane >> 2, c = lane & 3;
    int n = m0 + r;
    float v;
    if (is_ctx) v = (c < 2) ? s_ctx[2*(size_t)n + c] : f_ctx[2*(size_t)n + (c-2)];
    else { int tn = n - NCTX_TOT; v = (c < 2) ? s_test[2*(size_t)tn + c] : 0.f; }
    xin[r][c] = v;
  }

  { // L1
    const int c0 = lane * 4;
    float4 w4 = ldg4(&W1[4*256 + c0]);
    float4 w5 = ldg4(&W1[5*256 + c0]);
    float4 w6 = ldg4(&W1[6*256 + c0]);
    float4 w7 = ldg4(&W1[7*256 + c0]);
    float4 cbv = ldg4(&ctype[(is_ctx ? 256 : 0) + c0]);
    #pragma unroll
    for (int r = 0; r < 16; ++r) {
      float4 xi = *reinterpret_cast<const float4*>(&xin[r][0]);
      float4 a = cbv;
      fma4(a, xi.x, w4); fma4(a, xi.y, w5);
      fma4(a, xi.z, w6); fma4(a, xi.w, w7);
      half4 o = { (_Float16)gelu_f(a.x), (_Float16)gelu_f(a.y),
                  (_Float16)gelu_f(a.z), (_Float16)gelu_f(a.w) };
      *reinterpret_cast<half4*>(&h1t[r*264 + c0]) = o;
    }
  }

  { // L2
    f32x4 acc[8];
    #pragma unroll
    for (int j = 0; j < 8; ++j) {
      float bv = b2[16*j + cn];
      acc[j] = (f32x4){bv, bv, bv, bv};
    }
    const _Float16* aP = h1t + cn*264 + kg*8;
    #pragma unroll
    for (int ks = 0; ks < 8; ++ks) {
      half8 a = *reinterpret_cast<const half8*>(aP + ks*32);
      half8 bn[8];
      if (ks < 7) {
        #pragma unroll
        for (int j = 0; j < 8; ++j)
          bn[j] = *reinterpret_cast<const half8*>(bQ2 + j*4096 + (ks+1)*512);
      }
      #pragma unroll
      for (int j = 0; j < 8; ++j)
        acc[j] = __builtin_amdgcn_mfma_f32_16x16x32_f16(a, bb2[j], acc[j], 0, 0, 0);
      if (ks < 7) {
        #pragma unroll
        for (int j = 0; j < 8; ++j) bb2[j] = bn[j];
      }
    }
    #pragma unroll
    for (int j = 0; j < 8; ++j)
      #pragma unroll
      for (int r = 0; r < 4; ++r) {
        int m = kg*4 + r;
        h2[m*136 + 16*j + cn] = (_Float16)gelu_f(acc[j][r]);
      }
  }

  { // L3 + LN
    f32x4 acc[4];
    #pragma unroll
    for (int j = 0; j < 4; ++j) {
      float bv = b3[16*j + cn];
      acc[j] = (f32x4){bv, bv, bv, bv};
    }
    const _Float16* aP = h2 + cn*136 + kg*8;
    half8 bb[4];
    #pragma unroll
    for (int j = 0; j < 4; ++j)
      bb[j] = *reinterpret_cast<const half8*>(bQ3 + j*2048);
    #pragma unroll
    for (int ks = 0; ks < 4; ++ks) {
      half8 a = *reinterpret_cast<const half8*>(aP + ks*32);
      half8 bn[4];
      if (ks < 3) {
        #pragma unroll
        for (int j = 0; j < 4; ++j)
          bn[j] = *reinterpret_cast<const half8*>(bQ3 + j*2048 + (ks+1)*512);
      }
      #pragma unroll
      for (int j = 0; j < 4; ++j)
        acc[j] = __builtin_amdgcn_mfma_f32_16x16x32_f16(a, bb[j], acc[j], 0, 0, 0);
      if (ks < 3) {
        #pragma unroll
        for (int j = 0; j < 4; ++j) bb[j] = bn[j];
      }
    }
    float gv[4], bvv[4];
    #pragma unroll
    for (int j = 0; j < 4; ++j) { gv[j] = ln_g[16*j+cn]; bvv[j] = ln_b[16*j+cn]; }
    const bool is_test = !is_ctx;
    #pragma unroll
    for (int r = 0; r < 4; ++r) {
      float sv = 0.f, sq = 0.f;
      #pragma unroll
      for (int j = 0; j < 4; ++j) {
        float v = acc[j][r];
        sv += v; sq += v*v;
      }
      #pragma unroll
      for (int o = 1; o < 16; o <<= 1) {
        sv += __shfl_xor(sv, o);
        sq += __shfl_xor(sq, o);
      }
      float mean = sv * (1.0f/64.0f);
      float var  = sq * (1.0f/64.0f) - mean*mean;
      float rstd = rsqrtf(var + 1e-6f);
      int m = kg*4 + r;
      #pragma unroll
      for (int j = 0; j < 4; ++j) {
        float v = (acc[j][r] - mean) * rstd * gv[j] + bvv[j];
        nodh[m*72 + 16*j + cn] = (_Float16)v;
        if (is_test)
          nodes[(size_t)(m0 + m)*64 + 16*j + cn] = v;
      }
    }
  }

  { // xp(@fp16) = LN @ Wg, plus per-head xps/xpd emission
    f32x4 acc[4];
    #pragma unroll
    for (int j = 0; j < 4; ++j) acc[j] = (f32x4){0.f, 0.f, 0.f, 0.f};
    const _Float16* aP = nodh + cn*72 + kg*8;
    half8 bg0[4], bg1[4];
    #pragma unroll
    for (int j = 0; j < 4; ++j) {
      bg0[j] = *reinterpret_cast<const half8*>(bQg + j*1024);
      bg1[j] = *reinterpret_cast<const half8*>(bQg + j*1024 + 512);
    }
    half8 a0 = *reinterpret_cast<const half8*>(aP);
    half8 a1 = *reinterpret_cast<const half8*>(aP + 32);
    #pragma unroll
    for (int j = 0; j < 4; ++j)
      acc[j] = __builtin_amdgcn_mfma_f32_16x16x32_f16(a0, bg0[j], acc[j], 0, 0, 0);
    #pragma unroll
    for (int j = 0; j < 4; ++j)
      acc[j] = __builtin_amdgcn_mfma_f32_16x16x32_f16(a1, bg1[j], acc[j], 0, 0, 0);
    #pragma unroll
    for (int r = 0; r < 4; ++r) {
      int m = kg*4 + r;
      #pragma unroll
      for (int j = 0; j < 4; ++j)
        xph[(size_t)(m0 + m)*64 + 16*j + cn] = (_Float16)acc[j][r];
    }
    const float* av = is_ctx ? a_src : a_dst;
    float av0 = av[cn], av1 = av[16+cn], av2 = av[32+cn], av3 = av[48+cn];
    #pragma unroll
    for (int r = 0; r < 4; ++r) {
      float p0 = acc[0][r]*av0, p1 = acc[1][r]*av1;
      float p2 = acc[2][r]*av2, p3 = acc[3][r]*av3;
      #pragma unroll
      for (int o = 1; o < 16; o <<= 1) {
        p0 += __shfl_xor(p0, o); p1 += __shfl_xor(p1, o);
        p2 += __shfl_xor(p2, o); p3 += __shfl_xor(p3, o);
      }
      if (cn == 0) {
        int m = kg*4 + r;
        float4 v = make_float4(p0, p1, p2, p3);
        if (is_ctx)
          *reinterpret_cast<float4*>(&xps[(size_t)(m0 + m)*4]) = v;
        else
          *reinterpret_cast<float4*>(&xpd[(size_t)(m0 + m - NCTX_TOT)*4]) = v;
      }
    }
  }
}

// ---------------------------------------------------------------------------
// Back kernel (R15 verbatim): 4 waves per block share one 16-row tile
// (grid 1024 x 256). attn 4 rows/wave; pack fragments read once per block;
// L1 wave wv owns j-tiles wv*4..wv*4+3; L2 wave wv owns j = wv; 4-partial
// L3 combine via LDS.
// ---------------------------------------------------------------------------
__global__ __launch_bounds__(256, 4) void back_kernel(
    const float* __restrict__ s_ctx, const float* __restrict__ s_test,
    const _Float16* __restrict__ xph, const int* __restrict__ senders,
    const float* __restrict__ xps, const float* __restrict__ xpd,
    const float* __restrict__ We, const float* __restrict__ be,
    const float* __restrict__ nodes,
    const _Float16* __restrict__ H1P, const float* __restrict__ c1,
    const _Float16* __restrict__ H2P, const float* __restrict__ c2,
    const float* __restrict__ H3, const float* __restrict__ c3,
    float* __restrict__ outp)
{
  __shared__ __align__(16) _Float16 xinh[16*72];   // 2304 B (all 16 rows valid)
  __shared__ __align__(16) _Float16 h1[16*264];    // 8448 B
  __shared__ float pp[4][16][2];                   // 512 B L3 partials
  const int tid  = threadIdx.x;       // 0..255
  const int lane = tid & 63;
  const int wv   = tid >> 6;          // 0..3
  const int cn   = lane & 15;
  const int kg   = lane >> 4;
  const int bid  = blockIdx.x;                    // 1024
  const int L    = (bid & 7)*128 + (bid >> 3);    // XCD-contiguous
  const int row0 = L * 16;                        // test-local row base

  { // ---- attn: wave wv handles rows wv*4 .. wv*4+3 ----
    const int h  = kg;
    const int kk = cn;
    const int hb = lane & 48;
    const float we0 = We[h], we1 = We[4+h], beh = be[h];
    for (int rr = 0; rr < 4; ++rr) {
      const int rl   = wv*4 + rr;
      const int trow = row0 + rl;
      int s = senders[(size_t)trow*16 + kk];
      s = (s < 0) ? 0 : ((s >= NCTX_TOT) ? NCTX_TOT - 1 : s);  // safety clamp
      float pre = xps[(size_t)s*4 + h] + xpd[(size_t)trow*4 + h];
      float lr  = pre >= 0.f ? pre : 0.2f * pre;
      const float qx = s_test[(size_t)trow*2];
      const float qy = s_test[(size_t)trow*2 + 1];
      float ex = qx - s_ctx[(size_t)s*2];
      float ey = qy - s_ctx[(size_t)s*2 + 1];
      float sc = lr + fmaf(ex, we0, fmaf(ey, we1, beh));
      float mx = sc;
      #pragma unroll
      for (int o = 1; o < 16; o <<= 1) mx = fmaxf(mx, __shfl_xor(mx, o));
      float e = __expf(sc - mx);
      float sum = e;
      #pragma unroll
      for (int o = 1; o < 16; o <<= 1) sum += __shfl_xor(sum, o);
      float alpha = e / sum;
      // PV: lane = h*16+d reads alphas of its head via in-group shfl
      float outv = 0.f;
      #pragma unroll
      for (int k = 0; k < 16; ++k) {
        int   sk = __shfl(s, k);            // same across head groups
        float al = __shfl(alpha, hb + k);
        outv = fmaf(al, (float)xph[(size_t)sk*64 + lane], outv);
      }
      float xv = nodes[(size_t)(NCTX_TOT + trow)*64 + lane] + outv;
      xinh[rl*72 + lane] = (_Float16)xv;
    }
  }

  __syncthreads();

  // ---- head L1 (K=64, N=256): wave wv owns j-tiles wv*4 .. wv*4+3 ----
  {
    const _Float16* aP  = xinh + cn*72 + kg*8;
    const _Float16* bQ1 = H1P + lane*8;
    half8 a0 = *reinterpret_cast<const half8*>(aP);
    half8 a1 = *reinterpret_cast<const half8*>(aP + 32);
    f32x4 acc[4];
    #pragma unroll
    for (int j2 = 0; j2 < 4; ++j2) {
      const int jj = wv*4 + j2;
      float bv = c1[16*jj + cn];
      acc[j2] = (f32x4){bv, bv, bv, bv};
    }
    half8 b0[4], b1[4];
    #pragma unroll
    for (int j2 = 0; j2 < 4; ++j2) {
      const int jj = wv*4 + j2;
      b0[j2] = *reinterpret_cast<const half8*>(bQ1 + (jj*2 + 0)*512);
      b1[j2] = *reinterpret_cast<const half8*>(bQ1 + (jj*2 + 1)*512);
    }
    #pragma unroll
    for (int j2 = 0; j2 < 4; ++j2)
      acc[j2] = __builtin_amdgcn_mfma_f32_16x16x32_f16(a0, b0[j2], acc[j2], 0, 0, 0);
    #pragma unroll
    for (int j2 = 0; j2 < 4; ++j2)
      acc[j2] = __builtin_amdgcn_mfma_f32_16x16x32_f16(a1, b1[j2], acc[j2], 0, 0, 0);
    #pragma unroll
    for (int j2 = 0; j2 < 4; ++j2) {
      const int jj = wv*4 + j2;
      #pragma unroll
      for (int r = 0; r < 4; ++r)
        h1[(kg*4 + r)*264 + 16*jj + cn] = (_Float16)gelu_f(acc[j2][r]);
    }
  }

  __syncthreads();

  // ---- head L2 (K=256, N=64): wave wv owns j = wv, + L3 partials ----
  {
    f32x4 acc;
    {
      float bv = c2[16*wv + cn];
      acc = (f32x4){bv, bv, bv, bv};
    }
    const _Float16* aP  = h1 + cn*264 + kg*8;
    const _Float16* bQ2 = H2P + lane*8;
    half8 bb = *reinterpret_cast<const half8*>(bQ2 + wv*4096);
    #pragma unroll
    for (int ks = 0; ks < 8; ++ks) {
      half8 a = *reinterpret_cast<const half8*>(aP + ks*32);
      half8 bn;
      if (ks < 7)
        bn = *reinterpret_cast<const half8*>(bQ2 + wv*4096 + (ks+1)*512);
      acc = __builtin_amdgcn_mfma_f32_16x16x32_f16(a, bb, acc, 0, 0, 0);
      if (ks < 7) bb = bn;
    }
    // L3 partials: gelu, dot with this wave's H3 column slice, butterfly
    float h30 = H3[(16*wv + cn)*2 + 0];
    float h31 = H3[(16*wv + cn)*2 + 1];
    #pragma unroll
    for (int r = 0; r < 4; ++r) {
      float g  = gelu_f(acc[r]);
      float p0 = g * h30;
      float p1 = g * h31;
      #pragma unroll
      for (int o = 1; o < 16; o <<= 1) {
        p0 += __shfl_xor(p0, o);
        p1 += __shfl_xor(p1, o);
      }
      if (cn == 0) {
        pp[wv][kg*4 + r][0] = p0;
        pp[wv][kg*4 + r][1] = p1;
      }
    }
  }

  __syncthreads();

  // ---- combine partials + softplus + store (wave 0, lanes 0..15) ----
  if (wv == 0 && lane < 16) {
    const float c30 = c3[0], c31 = c3[1];
    float m  = pp[0][lane][0] + pp[1][lane][0] + pp[2][lane][0]
             + pp[3][lane][0] + c30;
    float sa = pp[0][lane][1] + pp[1][lane][1] + pp[2][lane][1]
             + pp[3][lane][1] + c31;
    float sv = fmaxf(sa, 0.f) + log1pf(__expf(-fabsf(sa)));  // softplus
    int row = row0 + lane;
    outp[(size_t)row*2 + 0] = m;
    outp[(size_t)row*2 + 1] = sv;
  }
}

// ---------------------------------------------------------------------------
extern "C" void kernel_launch(void* const* d_in, const int* in_sizes, int n_in,
                              void* d_out, int out_size, void* d_ws, size_t ws_size,
                              hipStream_t stream) {
  const float* s_ctx  = (const float*)d_in[0];
  const float* f_ctx  = (const float*)d_in[1];
  const float* s_test = (const float*)d_in[2];
  const float* emb    = (const float*)d_in[3];
  const float* W1 = (const float*)d_in[4];
  const float* b1 = (const float*)d_in[5];
  const float* W2 = (const float*)d_in[6];
  const float* b2 = (const float*)d_in[7];
  const float* W3 = (const float*)d_in[8];
  const float* b3 = (const float*)d_in[9];
  const float* ln_g = (const float*)d_in[10];
  const float* ln_b = (const float*)d_in[11];
  const float* Wg = (const float*)d_in[12];
  const float* a_src = (const float*)d_in[13];
  const float* a_dst = (const float*)d_in[14];
  const float* We = (const float*)d_in[15];
  const float* be = (const float*)d_in[16];
  const float* H1 = (const float*)d_in[17];
  const float* c1 = (const float*)d_in[18];
  const float* H2 = (const float*)d_in[19];
  const float* c2 = (const float*)d_in[20];
  const float* H3 = (const float*)d_in[21];
  const float* c3 = (const float*)d_in[22];

  float* nodes   = (float*)d_ws;                       // NTOT x 64 fp32
  _Float16* xph  = (_Float16*)(nodes + (size_t)NTOT*64);  // NTOT x 64 fp16
  int*   senders = (int*)(xph + (size_t)NTOT*64);      // NTEST_TOT x 16
  _Float16* W2P  = (_Float16*)(senders + (size_t)NTEST_TOT*16); // 32768 halves
  _Float16* W3P  = W2P + 32768;                        // 8192 halves
  _Float16* WgP  = W3P + 8192;                         // 4096 halves
  _Float16* H1P  = WgP + 4096;                         // 16384 halves
  _Float16* H2P  = H1P + 16384;                        // 16384 halves
  float*   ctype = (float*)(H2P + 16384);              // [2][256]
  float*   xps   = ctype + 512;                        // NCTX_TOT x 4
  float*   xpd   = xps + (size_t)NCTX_TOT*4;           // NTEST_TOT x 4
  float* outp    = (float*)d_out;

  hipLaunchKernelGGL(knn_prep_kernel, dim3(4136), dim3(256), 0, stream,
                     s_ctx, s_test, senders,
                     W1, b1, emb, W2, W3, Wg, H1, H2,
                     W2P, W3P, WgP, H1P, H2P, ctype);
  hipLaunchKernelGGL(mlp_kernel, dim3(768), dim3(256), 0, stream,
                     s_ctx, f_ctx, s_test, ctype, W1,
                     W2P, b2, W3P, b3, ln_g, ln_b, WgP,
                     a_src, a_dst, nodes, xph, xps, xpd);
  hipLaunchKernelGGL(back_kernel, dim3(1024), dim3(256), 0, stream,
                     s_ctx, s_test, xph, senders, xps, xpd, We, be,
                     nodes, H1P, c1, H2P, c2, H3, c3, outp);
}